// Round 3
// baseline (212.213 us; speedup 1.0000x reference)
//
#include <hip/hip_runtime.h>

// Trilinear grid_sample (align_corners=False, padding zeros) over a 128^3
// BINARY (0/1) grid, 8.4M points.
//
// Structure:
//  pack A: __ballot bitpack grid -> 256KB bitmask (coalesced, ~2us)
//  pack B: byte-table 129^3 from bitmask (4x u64-pair L2-hit loads/thread)
//          byte(x,y,z) bit k = voxel(x-1+(k&1), y-1+((k>>1)&1), z-1+(k>>2))
//  sample: 8 pts/thread, phase-split (addr -> 8 gathers in flight -> lerp),
//          nontemporal coord loads / out stores so the 96MB+32MB stream does
//          NOT evict the 2MB table from L2 (gathers must stay L2-hit).
//
// NOTE: __builtin_nontemporal_* requires native vector types, not
// HIP_vector_type -> use clang ext_vector_type floats.

typedef float fx4 __attribute__((ext_vector_type(4)));

constexpr int GS  = 128;
constexpr int TD  = GS + 1;                         // 129
constexpr size_t TBL_BYTES  = (size_t)TD * TD * TD; // ~2.05 MB
constexpr size_t MASK_WORDS = (size_t)GS * GS * GS / 64;  // 32768 u64 = 256 KB
constexpr size_t WS_NEEDED  = TBL_BYTES + 8 * MASK_WORDS + 64;

// ---------------------------------------------------------- pack A -------
__global__ __launch_bounds__(256)
void bitpack_kernel(const float* __restrict__ grid, unsigned long long* __restrict__ mask) {
    int gid = blockIdx.x * blockDim.x + threadIdx.x;   // exactly 128^3 threads
    float v = __builtin_nontemporal_load(&grid[gid]);
    unsigned long long m = __ballot(v != 0.0f);
    if ((threadIdx.x & 63) == 0) mask[gid >> 6] = m;
}

// ---------------------------------------------------------- pack B -------
__device__ __forceinline__ unsigned bit_at(unsigned long long lo, unsigned long long hi, int xi) {
    // xi in [-1, 128]; OOB -> 0. Row = 128 bits as (lo, hi).
    if ((unsigned)xi >= 128u) return 0u;
    unsigned long long w = (xi < 64) ? lo : hi;
    return (unsigned)((w >> (xi & 63)) & 1ull);
}

__global__ __launch_bounds__(256)
void table_kernel(const unsigned long long* __restrict__ mask, unsigned char* __restrict__ tbl) {
    int i = blockIdx.x * blockDim.x + threadIdx.x;
    if (i >= (int)TBL_BYTES) return;
    int x = i % TD;
    int t = i / TD;
    int y = t % TD;
    int z = t / TD;
    int x0 = x - 1;                   // corner voxel coords: {x0, x0+1} etc.
    unsigned byte = 0u;
#pragma unroll
    for (int dz = 0; dz < 2; ++dz) {
#pragma unroll
        for (int dy = 0; dy < 2; ++dy) {
            int yi = y - 1 + dy, zi = z - 1 + dz;
            unsigned long long lo = 0ull, hi = 0ull;
            if (((unsigned)yi < 128u) & ((unsigned)zi < 128u)) {
                int r = (zi * 128 + yi) * 2;
                lo = mask[r];
                hi = mask[r + 1];
            }
            unsigned b0 = bit_at(lo, hi, x0);
            unsigned b1 = bit_at(lo, hi, x0 + 1);
            int k = dy * 2 + dz * 4;
            byte |= (b0 << k) | (b1 << (k + 1));
        }
    }
    tbl[i] = (unsigned char)byte;
}

// ---------------------------------------------------------- sample -------
// 8 points/thread: 6x fx4 nt-loads, 8 L2-hit byte gathers, 2x fx4 nt-store.
__global__ __launch_bounds__(256)
void sample_packed(const unsigned char* __restrict__ tbl,
                   const float* __restrict__ coords,
                   float* __restrict__ out, int nt) {
    int t = blockIdx.x * blockDim.x + threadIdx.x;
    if (t >= nt) return;
    const fx4* c4 = (const fx4*)coords;
    fx4 q[6];
#pragma unroll
    for (int j = 0; j < 6; ++j) q[j] = __builtin_nontemporal_load(&c4[6 * t + j]);
    const float* f = (const float*)q;

    float wxa[8], wya[8], wza[8];
    int addr[8];
    // Phase 1: addresses + weights
#pragma unroll
    for (int i = 0; i < 8; ++i) {
        // ix = ((x+1)*128 - 1)*0.5 = x*64 + 63.5
        float ix = fmaf(f[3 * i + 0], 64.0f, 63.5f);
        float iy = fmaf(f[3 * i + 1], 64.0f, 63.5f);
        float iz = fmaf(f[3 * i + 2], 64.0f, 63.5f);
        float fx = floorf(ix), fy = floorf(iy), fz = floorf(iz);
        wxa[i] = ix - fx; wya[i] = iy - fy; wza[i] = iz - fz;
        int xb = (int)fx + 1, yb = (int)fy + 1, zb = (int)fz + 1;
        xb = min(max(xb, 0), GS); yb = min(max(yb, 0), GS); zb = min(max(zb, 0), GS);
        addr[i] = (zb * TD + yb) * TD + xb;
    }
    // Phase 2: all 8 gathers in flight together
    unsigned bytes[8];
#pragma unroll
    for (int i = 0; i < 8; ++i) bytes[i] = (unsigned)tbl[addr[i]];
    // Phase 3: interpolate
    float o[8];
#pragma unroll
    for (int i = 0; i < 8; ++i) {
        unsigned byte = bytes[i];
        float wx = wxa[i], wy = wya[i], wz = wza[i];
        float v0 = (float)( byte       & 1u);
        float v1 = (float)((byte >> 1) & 1u);
        float v2 = (float)((byte >> 2) & 1u);
        float v3 = (float)((byte >> 3) & 1u);
        float v4 = (float)((byte >> 4) & 1u);
        float v5 = (float)((byte >> 5) & 1u);
        float v6 = (float)((byte >> 6) & 1u);
        float v7 = (float)((byte >> 7) & 1u);
        float c00 = v0 + wx * (v1 - v0);
        float c10 = v2 + wx * (v3 - v2);
        float c01 = v4 + wx * (v5 - v4);
        float c11 = v6 + wx * (v7 - v6);
        float c0  = c00 + wy * (c10 - c00);
        float c1  = c01 + wy * (c11 - c01);
        o[i] = c0 + wz * (c1 - c0);
    }
    fx4* o4 = (fx4*)out;
    fx4 r0 = {o[0], o[1], o[2], o[3]};
    fx4 r1 = {o[4], o[5], o[6], o[7]};
    __builtin_nontemporal_store(r0, &o4[2 * t + 0]);
    __builtin_nontemporal_store(r1, &o4[2 * t + 1]);
}

// ------------------------------------------------- fallback (no ws) ------
__global__ __launch_bounds__(256)
void sample_direct(const float* __restrict__ grid,
                   const float* __restrict__ coords,
                   float* __restrict__ out, int nt) {
    int t = blockIdx.x * blockDim.x + threadIdx.x;
    if (t >= nt) return;
    const float4* c4 = (const float4*)coords;
    float4 a = c4[3 * t + 0];
    float4 b = c4[3 * t + 1];
    float4 c = c4[3 * t + 2];
    float xs[4] = {a.x, a.w, b.z, c.y};
    float ys[4] = {a.y, b.x, b.w, c.z};
    float zs[4] = {a.z, b.y, c.x, c.w};
    float4 res;
    float* r = &res.x;
#pragma unroll
    for (int i = 0; i < 4; ++i) {
        float ix = fmaf(xs[i], 64.0f, 63.5f);
        float iy = fmaf(ys[i], 64.0f, 63.5f);
        float iz = fmaf(zs[i], 64.0f, 63.5f);
        float fx = floorf(ix), fy = floorf(iy), fz = floorf(iz);
        float wx = ix - fx, wy = iy - fy, wz = iz - fz;
        int x0 = (int)fx, y0 = (int)fy, z0 = (int)fz;
        float v[8];
#pragma unroll
        for (int k = 0; k < 8; ++k) {
            int xi = x0 + (k & 1);
            int yi = y0 + ((k >> 1) & 1);
            int zi = z0 + (k >> 2);
            bool ok = ((unsigned)xi < (unsigned)GS) &
                      ((unsigned)yi < (unsigned)GS) &
                      ((unsigned)zi < (unsigned)GS);
            int xc = min(max(xi, 0), GS - 1);
            int yc = min(max(yi, 0), GS - 1);
            int zc = min(max(zi, 0), GS - 1);
            v[k] = grid[(zc * GS + yc) * GS + xc] * (ok ? 1.0f : 0.0f);
        }
        float c00 = v[0] + wx * (v[1] - v[0]);
        float c10 = v[2] + wx * (v[3] - v[2]);
        float c01 = v[4] + wx * (v[5] - v[4]);
        float c11 = v[6] + wx * (v[7] - v[6]);
        float c0  = c00 + wy * (c10 - c00);
        float c1  = c01 + wy * (c11 - c01);
        r[i] = c0 + wz * (c1 - c0);
    }
    ((float4*)out)[t] = res;
}

// -------------------------------------------------------------- launch ----
extern "C" void kernel_launch(void* const* d_in, const int* in_sizes, int n_in,
                              void* d_out, int out_size, void* d_ws, size_t ws_size,
                              hipStream_t stream) {
    const float* grid   = (const float*)d_in[0];
    const float* coords = (const float*)d_in[1];
    float* out = (float*)d_out;
    int npts = in_sizes[1] / 3;

    if (ws_size >= WS_NEEDED) {
        unsigned char* tbl = (unsigned char*)d_ws;
        // align mask region to 8 bytes after the table
        size_t mask_off = (TBL_BYTES + 7) & ~(size_t)7;
        unsigned long long* mask = (unsigned long long*)((char*)d_ws + mask_off);

        int vox = GS * GS * GS;                        // 2097152
        bitpack_kernel<<<vox / 256, 256, 0, stream>>>(grid, mask);
        int tbl_blocks = (int)((TBL_BYTES + 255) / 256);
        table_kernel<<<tbl_blocks, 256, 0, stream>>>(mask, tbl);

        int nt = npts / 8;                             // 1048576
        sample_packed<<<(nt + 255) / 256, 256, 0, stream>>>(tbl, coords, out, nt);
    } else {
        int nt = npts / 4;
        sample_direct<<<(nt + 255) / 256, 256, 0, stream>>>(grid, coords, out, nt);
    }
}

// Round 4
// 201.526 us; speedup vs baseline: 1.0530x; 1.0530x over previous
//
#include <hip/hip_runtime.h>

// Trilinear grid_sample (align_corners=False, zeros padding) over a 128^3
// BINARY grid, 8.4M random points.
//
// R4: scattered global gathers plateau at ~0.19 req/cyc/CU (MSHR x L2-latency
// bound; R1 4/thr == R3 8/thr proves ILP-insensitive). Fix: absorb the random
// access in LDS. Bitmask = 256KB; half (<=65 z-planes, 130KB) fits in CDNA4
// 160KB LDS. 256 blocks x 1024 thr; each block owns 32768 contiguous points;
// 2 slab passes: fill LDS slab -> rescan own coords (pass 2 hits L3) ->
// points in slab do 4x ds_read2_b32 row reads + lerp. All global traffic
// coalesced. Fallback to byte-table gather path if >64KB workgroup LDS is
// rejected (probed via hipOccupancyMaxActiveBlocksPerMultiprocessor).

typedef float fx4 __attribute__((ext_vector_type(4)));
typedef unsigned int u32;
typedef unsigned long long u64;

constexpr int GS = 128;
constexpr int TD = GS + 1;                              // 129 (fallback table)
constexpr size_t MASK_BYTES = (size_t)GS * GS * GS / 8; // 256 KB
constexpr size_t TBL_BYTES  = (size_t)TD * TD * TD;     // ~2.05 MB (fallback)
// ws layout: [mask 256KB][tbl ...] ; new path uses only mask
constexpr size_t WS_NEW = MASK_BYTES;
constexpr size_t WS_FB  = MASK_BYTES + TBL_BYTES + 64;

constexpr int NP_MAX = 65;                              // planes in LDS slab
constexpr size_t SLAB_LDS = (size_t)NP_MAX * 2048 + 16; // 133,136 B

// ---------------------------------------------------------- bitpack ------
// mask u32 word layout: word = (z*128 + y)*4 + (x>>5); bit = x&31.
__global__ __launch_bounds__(256)
void bitpack_kernel(const float* __restrict__ grid, u64* __restrict__ mask) {
    int gid = blockIdx.x * blockDim.x + threadIdx.x;    // 128^3 threads
    float v = grid[gid];
    u64 m = __ballot(v != 0.0f);
    if ((threadIdx.x & 63) == 0) mask[gid >> 6] = m;
}

// ---------------------------------------------------------- slab sample --
__global__ __launch_bounds__(1024, 4)
void sample_slab(const u32* __restrict__ mask32,
                 const float* __restrict__ coords,
                 float* __restrict__ out, int npts) {
    extern __shared__ u32 lds[];
    const int tid = threadIdx.x;
    const int nthr = 1024;
    const int ptsPerBlock = npts / gridDim.x;           // 32768
    const int base = blockIdx.x * ptsPerBlock;
    const int ngroups = ptsPerBlock / (4 * nthr);       // 8
    const fx4* c4 = (const fx4*)coords;

#pragma unroll 1
    for (int s = 0; s < 2; ++s) {
        // slab s: voxel z-planes [pz0, pz0+np); base-cell zb range [zlo,zhi]
        const int pz0 = s ? 63 : 0;
        const int np  = s ? 65 : 64;
        const int zlo = s ? 64 : 0;
        const int zhi = s ? 128 : 63;
        __syncthreads();
        {   // fill LDS slab (linear copy of plane range; 128KB/130KB)
            const int nwords = np * 512;                // 512 u32 per plane
            const u32* src = mask32 + pz0 * 512;
            for (int i = tid; i < nwords; i += nthr) lds[i] = src[i];
            if (tid == 0) lds[nwords] = 0;              // overread pad (k=3,w+1)
        }
        __syncthreads();

        for (int g = 0; g < ngroups; ++g) {
            int grp = base / 4 + g * nthr + tid;        // group of 4 points
            fx4 q0 = c4[3 * grp + 0];
            fx4 q1 = c4[3 * grp + 1];
            fx4 q2 = c4[3 * grp + 2];
            float f[12] = {q0.x, q0.y, q0.z, q0.w,
                           q1.x, q1.y, q1.z, q1.w,
                           q2.x, q2.y, q2.z, q2.w};
#pragma unroll
            for (int j = 0; j < 4; ++j) {
                float ixf = fmaf(f[3 * j + 0], 64.0f, 63.5f);
                float iyf = fmaf(f[3 * j + 1], 64.0f, 63.5f);
                float izf = fmaf(f[3 * j + 2], 64.0f, 63.5f);
                float fxx = floorf(ixf), fyy = floorf(iyf), fzz = floorf(izf);
                float wx = ixf - fxx, wy = iyf - fyy, wz = izf - fzz;
                int x0 = (int)fxx, y0 = (int)fyy, z0 = (int)fzz; // [-1,127]
                int zb = z0 + 1;                                 // [0,128]
                if (zb >= zlo && zb <= zhi) {
                    int xc = x0 < 0 ? 0 : x0;
                    int k  = xc >> 5;              // word within 16B row, [0,3]
                    int p0 = x0 - (k << 5);        // bit pos, [-1,31]
                    u32 okx0 = (u32)(x0 >= 0);
                    u32 okx1 = (u32)(x0 <= 126);
                    float r[2][2];
#pragma unroll
                    for (int dz = 0; dz < 2; ++dz) {
                        int zl = z0 + dz - pz0;
                        u32 vz = (u32)((unsigned)zl < (unsigned)np);
#pragma unroll
                        for (int dy = 0; dy < 2; ++dy) {
                            int yr = y0 + dy;
                            u32 v = vz & (u32)((unsigned)yr < 128u);
                            int widx = v ? (zl * 128 + yr) * 4 + k : 0;
                            u32 w0 = lds[widx];
                            u32 w1 = lds[widx + 1];       // -> ds_read2_b32
                            u64 vv = (u64)w0 | ((u64)w1 << 32);
                            int b0 = (int)((u32)(vv >> (p0 & 63)) & 1u & okx0 & v);
                            int b1 = (int)((u32)(vv >> ((p0 + 1) & 63)) & 1u & okx1 & v);
                            r[dz][dy] = fmaf(wx, (float)(b1 - b0), (float)b0);
                        }
                    }
                    float c0 = fmaf(wy, r[0][1] - r[0][0], r[0][0]);
                    float c1 = fmaf(wy, r[1][1] - r[1][0], r[1][0]);
                    out[grp * 4 + j] = fmaf(wz, c1 - c0, c0);
                }
            }
        }
    }
}

// ------------------------------------------------- fallback path ---------
__device__ __forceinline__ unsigned bit_at(u64 lo, u64 hi, int xi) {
    if ((unsigned)xi >= 128u) return 0u;
    u64 w = (xi < 64) ? lo : hi;
    return (unsigned)((w >> (xi & 63)) & 1ull);
}

__global__ __launch_bounds__(256)
void table_kernel(const u64* __restrict__ mask, unsigned char* __restrict__ tbl) {
    int i = blockIdx.x * blockDim.x + threadIdx.x;
    if (i >= (int)TBL_BYTES) return;
    int x = i % TD;
    int t = i / TD;
    int y = t % TD;
    int z = t / TD;
    int x0 = x - 1;
    unsigned byte = 0u;
#pragma unroll
    for (int dz = 0; dz < 2; ++dz) {
#pragma unroll
        for (int dy = 0; dy < 2; ++dy) {
            int yi = y - 1 + dy, zi = z - 1 + dz;
            u64 lo = 0ull, hi = 0ull;
            if (((unsigned)yi < 128u) & ((unsigned)zi < 128u)) {
                int r = (zi * 128 + yi) * 2;
                lo = mask[r];
                hi = mask[r + 1];
            }
            int kk = dy * 2 + dz * 4;
            byte |= (bit_at(lo, hi, x0) << kk) | (bit_at(lo, hi, x0 + 1) << (kk + 1));
        }
    }
    tbl[i] = (unsigned char)byte;
}

__global__ __launch_bounds__(256)
void sample_packed(const unsigned char* __restrict__ tbl,
                   const float* __restrict__ coords,
                   float* __restrict__ out, int nt) {
    int t = blockIdx.x * blockDim.x + threadIdx.x;
    if (t >= nt) return;
    const fx4* c4 = (const fx4*)coords;
    fx4 q[6];
#pragma unroll
    for (int j = 0; j < 6; ++j) q[j] = c4[6 * t + j];
    const float* f = (const float*)q;
    float wxa[8], wya[8], wza[8];
    int addr[8];
#pragma unroll
    for (int i = 0; i < 8; ++i) {
        float ix = fmaf(f[3 * i + 0], 64.0f, 63.5f);
        float iy = fmaf(f[3 * i + 1], 64.0f, 63.5f);
        float iz = fmaf(f[3 * i + 2], 64.0f, 63.5f);
        float fx = floorf(ix), fy = floorf(iy), fz = floorf(iz);
        wxa[i] = ix - fx; wya[i] = iy - fy; wza[i] = iz - fz;
        int xb = (int)fx + 1, yb = (int)fy + 1, zb = (int)fz + 1;
        addr[i] = (zb * TD + yb) * TD + xb;
    }
    unsigned bytes[8];
#pragma unroll
    for (int i = 0; i < 8; ++i) bytes[i] = (unsigned)tbl[addr[i]];
    float o[8];
#pragma unroll
    for (int i = 0; i < 8; ++i) {
        unsigned byte = bytes[i];
        float wx = wxa[i], wy = wya[i], wz = wza[i];
        float v0 = (float)( byte       & 1u);
        float v1 = (float)((byte >> 1) & 1u);
        float v2 = (float)((byte >> 2) & 1u);
        float v3 = (float)((byte >> 3) & 1u);
        float v4 = (float)((byte >> 4) & 1u);
        float v5 = (float)((byte >> 5) & 1u);
        float v6 = (float)((byte >> 6) & 1u);
        float v7 = (float)((byte >> 7) & 1u);
        float c00 = v0 + wx * (v1 - v0);
        float c10 = v2 + wx * (v3 - v2);
        float c01 = v4 + wx * (v5 - v4);
        float c11 = v6 + wx * (v7 - v6);
        float c0  = c00 + wy * (c10 - c00);
        float c1  = c01 + wy * (c11 - c01);
        o[i] = c0 + wz * (c1 - c0);
    }
    fx4* o4 = (fx4*)out;
    fx4 r0 = {o[0], o[1], o[2], o[3]};
    fx4 r1 = {o[4], o[5], o[6], o[7]};
    o4[2 * t + 0] = r0;
    o4[2 * t + 1] = r1;
}

// -------------------------------------------------------------- launch ----
extern "C" void kernel_launch(void* const* d_in, const int* in_sizes, int n_in,
                              void* d_out, int out_size, void* d_ws, size_t ws_size,
                              hipStream_t stream) {
    const float* grid   = (const float*)d_in[0];
    const float* coords = (const float*)d_in[1];
    float* out = (float*)d_out;
    int npts = in_sizes[1] / 3;                          // 8388608

    u64* mask = (u64*)d_ws;                              // 256 KB @ offset 0
    int vox = GS * GS * GS;

    // Probe legality of 133KB dynamic LDS (capture-safe, deterministic).
    (void)hipFuncSetAttribute((const void*)sample_slab,
                              hipFuncAttributeMaxDynamicSharedMemorySize,
                              (int)SLAB_LDS);
    int nb = 0;
    hipError_t oe = hipOccupancyMaxActiveBlocksPerMultiprocessor(
        &nb, sample_slab, 1024, SLAB_LDS);
    bool slab_ok = (oe == hipSuccess) && (nb >= 1) && (ws_size >= WS_NEW) &&
                   (npts % (256 * 4096) == 0);

    if (slab_ok) {
        bitpack_kernel<<<vox / 256, 256, 0, stream>>>(grid, mask);
        sample_slab<<<256, 1024, SLAB_LDS, stream>>>((const u32*)mask, coords, out, npts);
    } else if (ws_size >= WS_FB) {
        unsigned char* tbl = (unsigned char*)d_ws + MASK_BYTES;
        bitpack_kernel<<<vox / 256, 256, 0, stream>>>(grid, mask);
        int tbl_blocks = (int)((TBL_BYTES + 255) / 256);
        table_kernel<<<tbl_blocks, 256, 0, stream>>>(mask, tbl);
        int nt = npts / 8;
        sample_packed<<<(nt + 255) / 256, 256, 0, stream>>>(tbl, coords, out, nt);
    }
}

// Round 5
// 194.744 us; speedup vs baseline: 1.0897x; 1.0348x over previous
//
#include <hip/hip_runtime.h>

// Trilinear grid_sample (align_corners=False, zeros padding) over a 128^3
// BINARY grid, 8.4M random points.
//
// R5: LDS-slab approach, restructured from R4's 86us version:
//  - per-point state (packed rowinfo + wx,wy,wz) kept in VGPRs across all
//    3 slab passes -> coords read ONCE, out written ONCE (dwordx4, no RMW)
//  - padded 130^3 bitmask (5 u32/row, zero borders) -> inner loop has NO
//    boundary predication: 4x (ds_read2_b32 + 64b shift + lerp) per point
//  - 3 slabs x <=46 planes = 119.6KB dynamic LDS (133KB probed legal in R4)

typedef float fx4 __attribute__((ext_vector_type(4)));
typedef unsigned int u32;
typedef unsigned int ux4 __attribute__((ext_vector_type(4)));
typedef unsigned long long u64;

constexpr int GS = 128;
// padded mask: planes PZ in [0,129], rows PY in [0,129], 5 u32 words/row.
// bit PX in row = voxel x = PX-1 (0 if OOB). Query window [PX, PX+1], PX<=128.
constexpr int PROW_W  = 5;
constexpr int PPLANE_W = 130 * PROW_W;            // 650 words/plane
constexpr int PMASK_WORDS = 130 * PPLANE_W;       // 84,500
constexpr size_t PMASK_BYTES = (size_t)PMASK_WORDS * 4;   // 338,000

constexpr size_t MASK_BYTES = (size_t)GS * GS * GS / 8;   // 256 KB ballot mask
constexpr size_t MASK_OFF   = (PMASK_BYTES + 63) & ~(size_t)63;
constexpr size_t WS_MAIN    = MASK_OFF + MASK_BYTES;

// fallback (R3 byte-table gather path)
constexpr int TD = GS + 1;
constexpr size_t TBL_BYTES = (size_t)TD * TD * TD;
constexpr size_t TBL_OFF   = MASK_OFF + MASK_BYTES;
constexpr size_t WS_FB     = TBL_OFF + TBL_BYTES;

// slabs: s0 planes [0,46) PZ 0..44 | s1 [44,90) PZ 45..88 | s2 [88,130) PZ 89..128
constexpr int SLAB_ALLOC_WORDS = 46 * PPLANE_W + 1;       // 29,901 (+1 overread pad)
constexpr size_t SLAB_LDS = (size_t)SLAB_ALLOC_WORDS * 4; // 119,604 B

// ---------------------------------------------------------- bitpack ------
__global__ __launch_bounds__(256)
void bitpack_kernel(const float* __restrict__ grid, u64* __restrict__ mask) {
    int gid = blockIdx.x * blockDim.x + threadIdx.x;   // 128^3 threads
    float v = grid[gid];
    u64 m = __ballot(v != 0.0f);
    if ((threadIdx.x & 63) == 0) mask[gid >> 6] = m;
}

// ---------------------------------------------------------- padmask ------
// padded word k of row (py,pz): bits PX=32k+i -> voxel x=32k+i-1
//   w = (v[k-1] >> 31) | (v[k] << 1), v[] = raw row words, v OOB = 0
__global__ __launch_bounds__(256)
void padmask_kernel(const u32* __restrict__ mask32, u32* __restrict__ pmask) {
    int i = blockIdx.x * blockDim.x + threadIdx.x;
    if (i >= PMASK_WORDS) return;
    int k = i % PROW_W;
    int r = i / PROW_W;
    int py = r % 130;
    int pz = r / 130;
    int y = py - 1, z = pz - 1;
    u32 w = 0;
    if (((unsigned)y < 128u) & ((unsigned)z < 128u)) {
        const u32* vrow = mask32 + (z * 128 + y) * 4;
        u32 lo = (k >= 1) ? vrow[k - 1] : 0u;
        u32 hi = (k < 4) ? vrow[k] : 0u;
        w = (lo >> 31) | (hi << 1);
    }
    pmask[i] = w;
}

// ---------------------------------------------------------- sample -------
__global__ __launch_bounds__(1024, 4)
void sample_slab3(const u32* __restrict__ pmask,
                  const float* __restrict__ coords,
                  float* __restrict__ out) {
    extern __shared__ u32 lds[];
    const int tid = threadIdx.x;
    const int T = blockIdx.x * 1024 + tid;
    const fx4* c4 = (const fx4*)coords;
    fx4 q[6];
#pragma unroll
    for (int j = 0; j < 6; ++j) q[j] = c4[6 * T + j];
    const float* f = (const float*)q;

    u32 pr[8];
    float wx[8], wy[8], wz[8], o[8];
#pragma unroll
    for (int j = 0; j < 8; ++j) {
        float ix = fmaf(f[3 * j + 0], 64.0f, 63.5f);   // ((x+1)*128-1)/2
        float iy = fmaf(f[3 * j + 1], 64.0f, 63.5f);
        float iz = fmaf(f[3 * j + 2], 64.0f, 63.5f);
        float fx = floorf(ix), fy = floorf(iy), fz = floorf(iz);
        wx[j] = ix - fx; wy[j] = iy - fy; wz[j] = iz - fz;
        int X  = (int)fx + 1;                          // [0,128] padded coords
        int Y  = (int)fy + 1;
        int PZ = (int)fz + 1;
        int k = X >> 5, p = X & 31;
        u32 R = (u32)((PZ * 130 + Y) * PROW_W + k);    // < 2^17
        pr[j] = R | ((u32)p << 20) | ((u32)PZ << 25);
        o[j] = 0.0f;
    }

#pragma unroll 1
    for (int s = 0; s < 3; ++s) {
        const int p0 = (s == 0) ? 0 : (s == 1 ? 44 : 88);
        const int np = (s == 2) ? 42 : 46;
        const int lo = (s == 0) ? 0 : (s == 1 ? 45 : 89);
        const int hi = (s == 0) ? 44 : (s == 1 ? 88 : 128);
        __syncthreads();
        {   // coalesced vec4 fill of the slab
            const int nv = np * PPLANE_W / 4;          // 7475 / 7475 / 6825
            const ux4* src = (const ux4*)(pmask + p0 * PPLANE_W);
            ux4* dst = (ux4*)lds;
            for (int i = tid; i < nv; i += 1024) dst[i] = src[i];
        }
        __syncthreads();
#pragma unroll
        for (int j = 0; j < 8; ++j) {
            int PZ = (int)(pr[j] >> 25);
            if ((unsigned)(PZ - lo) > (unsigned)(hi - lo)) continue;
            int p  = (int)((pr[j] >> 20) & 31u);
            int rb = (int)(pr[j] & 0xFFFFFu) - p0 * PPLANE_W;
            int rb2 = rb + PPLANE_W;
            // 4 rows: (z,y),(z,y+1),(z+1,y),(z+1,y+1); w[k],w[k+1] per row
            u32 a0 = lds[rb],      a1 = lds[rb + 1];
            u32 b0 = lds[rb + 5],  b1 = lds[rb + 6];
            u32 c0 = lds[rb2],     c1 = lds[rb2 + 1];
            u32 d0 = lds[rb2 + 5], d1 = lds[rb2 + 6];
            u32 t00 = (u32)((((u64)a1 << 32) | a0) >> p) & 3u;
            u32 t01 = (u32)((((u64)b1 << 32) | b0) >> p) & 3u;
            u32 t10 = (u32)((((u64)c1 << 32) | c0) >> p) & 3u;
            u32 t11 = (u32)((((u64)d1 << 32) | d0) >> p) & 3u;
            float w = wx[j];
            float r00 = fmaf(w, (float)(t00 >> 1) - (float)(t00 & 1u), (float)(t00 & 1u));
            float r01 = fmaf(w, (float)(t01 >> 1) - (float)(t01 & 1u), (float)(t01 & 1u));
            float r10 = fmaf(w, (float)(t10 >> 1) - (float)(t10 & 1u), (float)(t10 & 1u));
            float r11 = fmaf(w, (float)(t11 >> 1) - (float)(t11 & 1u), (float)(t11 & 1u));
            float cy0 = fmaf(wy[j], r01 - r00, r00);
            float cy1 = fmaf(wy[j], r11 - r10, r10);
            o[j] = fmaf(wz[j], cy1 - cy0, cy0);
        }
    }
    fx4* o4 = (fx4*)out;
    fx4 r0 = {o[0], o[1], o[2], o[3]};
    fx4 r1 = {o[4], o[5], o[6], o[7]};
    o4[2 * T]     = r0;
    o4[2 * T + 1] = r1;
}

// ------------------------------------------------- fallback path (R3) ----
__device__ __forceinline__ unsigned bit_at(u64 lo, u64 hi, int xi) {
    if ((unsigned)xi >= 128u) return 0u;
    u64 w = (xi < 64) ? lo : hi;
    return (unsigned)((w >> (xi & 63)) & 1ull);
}

__global__ __launch_bounds__(256)
void table_kernel(const u64* __restrict__ mask, unsigned char* __restrict__ tbl) {
    int i = blockIdx.x * blockDim.x + threadIdx.x;
    if (i >= (int)TBL_BYTES) return;
    int x = i % TD;
    int t = i / TD;
    int y = t % TD;
    int z = t / TD;
    int x0 = x - 1;
    unsigned byte = 0u;
#pragma unroll
    for (int dz = 0; dz < 2; ++dz) {
#pragma unroll
        for (int dy = 0; dy < 2; ++dy) {
            int yi = y - 1 + dy, zi = z - 1 + dz;
            u64 lo = 0ull, hi = 0ull;
            if (((unsigned)yi < 128u) & ((unsigned)zi < 128u)) {
                int r = (zi * 128 + yi) * 2;
                lo = mask[r];
                hi = mask[r + 1];
            }
            int kk = dy * 2 + dz * 4;
            byte |= (bit_at(lo, hi, x0) << kk) | (bit_at(lo, hi, x0 + 1) << (kk + 1));
        }
    }
    tbl[i] = (unsigned char)byte;
}

__global__ __launch_bounds__(256)
void sample_packed(const unsigned char* __restrict__ tbl,
                   const float* __restrict__ coords,
                   float* __restrict__ out, int nt) {
    int t = blockIdx.x * blockDim.x + threadIdx.x;
    if (t >= nt) return;
    const fx4* c4 = (const fx4*)coords;
    fx4 q[6];
#pragma unroll
    for (int j = 0; j < 6; ++j) q[j] = c4[6 * t + j];
    const float* f = (const float*)q;
    float wxa[8], wya[8], wza[8];
    int addr[8];
#pragma unroll
    for (int i = 0; i < 8; ++i) {
        float ix = fmaf(f[3 * i + 0], 64.0f, 63.5f);
        float iy = fmaf(f[3 * i + 1], 64.0f, 63.5f);
        float iz = fmaf(f[3 * i + 2], 64.0f, 63.5f);
        float fx = floorf(ix), fy = floorf(iy), fz = floorf(iz);
        wxa[i] = ix - fx; wya[i] = iy - fy; wza[i] = iz - fz;
        int xb = (int)fx + 1, yb = (int)fy + 1, zb = (int)fz + 1;
        addr[i] = (zb * TD + yb) * TD + xb;
    }
    unsigned bytes[8];
#pragma unroll
    for (int i = 0; i < 8; ++i) bytes[i] = (unsigned)tbl[addr[i]];
    float o[8];
#pragma unroll
    for (int i = 0; i < 8; ++i) {
        unsigned byte = bytes[i];
        float wx = wxa[i], wy = wya[i], wz = wza[i];
        float v0 = (float)( byte       & 1u);
        float v1 = (float)((byte >> 1) & 1u);
        float v2 = (float)((byte >> 2) & 1u);
        float v3 = (float)((byte >> 3) & 1u);
        float v4 = (float)((byte >> 4) & 1u);
        float v5 = (float)((byte >> 5) & 1u);
        float v6 = (float)((byte >> 6) & 1u);
        float v7 = (float)((byte >> 7) & 1u);
        float c00 = v0 + wx * (v1 - v0);
        float c10 = v2 + wx * (v3 - v2);
        float c01 = v4 + wx * (v5 - v4);
        float c11 = v6 + wx * (v7 - v6);
        float c0  = c00 + wy * (c10 - c00);
        float c1  = c01 + wy * (c11 - c01);
        o[i] = c0 + wz * (c1 - c0);
    }
    fx4* o4 = (fx4*)out;
    fx4 r0 = {o[0], o[1], o[2], o[3]};
    fx4 r1 = {o[4], o[5], o[6], o[7]};
    o4[2 * t + 0] = r0;
    o4[2 * t + 1] = r1;
}

// -------------------------------------------------------------- launch ----
extern "C" void kernel_launch(void* const* d_in, const int* in_sizes, int n_in,
                              void* d_out, int out_size, void* d_ws, size_t ws_size,
                              hipStream_t stream) {
    const float* grid   = (const float*)d_in[0];
    const float* coords = (const float*)d_in[1];
    float* out = (float*)d_out;
    int npts = in_sizes[1] / 3;                          // 8,388,608
    int vox = GS * GS * GS;

    u32* pmask = (u32*)d_ws;
    u64* mask  = (u64*)((char*)d_ws + MASK_OFF);

    // Probe legality of 119.6KB dynamic LDS (capture-safe, deterministic).
    (void)hipFuncSetAttribute((const void*)sample_slab3,
                              hipFuncAttributeMaxDynamicSharedMemorySize,
                              (int)SLAB_LDS);
    int nb = 0;
    hipError_t oe = hipOccupancyMaxActiveBlocksPerMultiprocessor(
        &nb, sample_slab3, 1024, SLAB_LDS);
    bool slab_ok = (oe == hipSuccess) && (nb >= 1) && (ws_size >= WS_MAIN) &&
                   (npts == 1024 * 1024 * 8);

    if (slab_ok) {
        bitpack_kernel<<<vox / 256, 256, 0, stream>>>(grid, mask);
        padmask_kernel<<<(PMASK_WORDS + 255) / 256, 256, 0, stream>>>((const u32*)mask, pmask);
        sample_slab3<<<1024, 1024, SLAB_LDS, stream>>>(pmask, coords, out);
    } else if (ws_size >= WS_FB) {
        unsigned char* tbl = (unsigned char*)d_ws + TBL_OFF;
        bitpack_kernel<<<vox / 256, 256, 0, stream>>>(grid, mask);
        table_kernel<<<(int)((TBL_BYTES + 255) / 256), 256, 0, stream>>>(mask, tbl);
        int nt = npts / 8;
        sample_packed<<<(nt + 255) / 256, 256, 0, stream>>>(tbl, coords, out, nt);
    }
}

// Round 6
// 194.369 us; speedup vs baseline: 1.0918x; 1.0019x over previous
//
#include <hip/hip_runtime.h>

// Trilinear grid_sample (align_corners=False, zeros padding) over a 128^3
// BINARY grid, 8.4M random points.
//
// R6: 2-pass LDS slab (R5 was 3-pass; divergence multiplier = #passes since
// every j-body runs whenever >=1 of 64 lanes is active).
//  - raw ballot bitmask rows (4 u32 = 16B per (z,y) row), no padded copy:
//    pass A: voxel planes 0..63  (131072 B) serves points zb in [0,63]
//    pass B: voxel planes 63..127 (133120 B + pad) serves zb in [64,128]
//  - x-window via ONE v_alignbit_b32 per row (funnel shift). x0=-1 handled
//    branch-free by mirroring wx -> 1-wx (then extracted (v0,v1) with b1
//    masked gives r = wx*v0 as required). x=127/straddle masked via 2-bit
//    row masks precomputed in the prologue.
//  - per-point state packed: pack1 = RA(16) | sft(5)<<16 | zb(8)<<21 |
//    dyf<<29 ; AM = 8x 4-bit row-mask nibbles. Coords read once, out once.

typedef float fx4 __attribute__((ext_vector_type(4)));
typedef unsigned int u32;
typedef unsigned int ux4 __attribute__((ext_vector_type(4)));
typedef unsigned long long u64;

constexpr int GS = 128;
constexpr size_t MASK_BYTES = (size_t)GS * GS * GS / 8;   // 256 KB
// LDS: pass B needs 33280 words + 1 pad
constexpr int SLAB_WORDS = 33281;
constexpr size_t SLAB_LDS = (size_t)SLAB_WORDS * 4;       // 133,124 B (probed OK in R4)

// fallback (byte-table gather path)
constexpr int TD = GS + 1;
constexpr size_t TBL_BYTES = (size_t)TD * TD * TD;
constexpr size_t TBL_OFF   = (MASK_BYTES + 63) & ~(size_t)63;
constexpr size_t WS_FB     = TBL_OFF + TBL_BYTES;

// ---------------------------------------------------------- bitpack ------
__global__ __launch_bounds__(256)
void bitpack_kernel(const float* __restrict__ grid, u64* __restrict__ mask) {
    int gid = blockIdx.x * blockDim.x + threadIdx.x;   // 128^3 threads
    float v = grid[gid];
    u64 m = __ballot(v != 0.0f);
    if ((threadIdx.x & 63) == 0) mask[gid >> 6] = m;
}

// ---------------------------------------------------------- sample -------
__global__ __launch_bounds__(1024, 4)
void sample_2p(const u32* __restrict__ mask32,
               const float* __restrict__ coords,
               float* __restrict__ out) {
    extern __shared__ u32 lds[];
    const int tid = threadIdx.x;
    const int T = blockIdx.x * 1024 + tid;
    const fx4* c4 = (const fx4*)coords;
    fx4 q[6];
#pragma unroll
    for (int j = 0; j < 6; ++j) q[j] = c4[6 * T + j];
    const float* f = (const float*)q;

    u32 pack1[8];
    u32 AM = 0;
    float wx[8], wy[8], wz[8], o[8];
#pragma unroll
    for (int j = 0; j < 8; ++j) {
        float ix = fmaf(f[3 * j + 0], 64.0f, 63.5f);   // ((x+1)*128-1)/2
        float iy = fmaf(f[3 * j + 1], 64.0f, 63.5f);
        float iz = fmaf(f[3 * j + 2], 64.0f, 63.5f);
        float fx = floorf(ix), fy = floorf(iy), fz = floorf(iz);
        float w0 = ix - fx;
        wy[j] = iy - fy; wz[j] = iz - fz;
        int x0 = (int)fx, y0 = (int)fy, z0 = (int)fz;  // [-1,127]
        int zb = z0 + 1;                               // [0,128]
        // x handling: mirror trick for x0==-1
        bool flip = (x0 < 0);
        wx[j] = flip ? 1.0f - w0 : w0;
        int xc = flip ? 0 : x0;
        int sft = xc & 31;                             // alignbit shift
        u32 xm = ((u32)x0 <= 126u) ? 3u : 1u;          // b1 masked at edges
        u32 vy0 = (u32)(y0 >= 0);
        u32 vy1 = (u32)((u32)y0 <= 126u);
        u32 a0 = vy0 ? xm : 0u;
        u32 a1 = vy1 ? xm : 0u;
        u32 am = a0 | (a1 << 2);
        u32 dyf = vy0 & vy1;                           // row y+1 at +16B?
        int y0c = y0 < 0 ? 0 : y0;
        int z0c = z0 < 0 ? 0 : z0;
        u32 RA = (u32)(((z0c << 7) + y0c) * 4 + (xc >> 5));  // word idx, 16b
        pack1[j] = RA | ((u32)sft << 16) | ((u32)zb << 21) | (dyf << 29);
        AM |= am << (4 * j);
        o[j] = 0.0f;
    }

#pragma unroll 1
    for (int s = 0; s < 2; ++s) {
        const int base_w = s ? 32256 : 0;              // 63*512
        const int nv4    = s ? 8320 : 8192;            // ux4 count
        __syncthreads();
        {   // coalesced vec4 slab fill
            const ux4* src = (const ux4*)(mask32 + base_w);
            ux4* dst = (ux4*)lds;
            for (int i = tid; i < nv4; i += 1024) dst[i] = src[i];
            if (s && tid == 0) lds[33280] = 0;         // straddle pad
        }
        __syncthreads();
#pragma unroll
        for (int j = 0; j < 8; ++j) {
            u32 p1 = pack1[j];
            int zb = (int)((p1 >> 21) & 0xFF);
            if ((zb < 64) != (s == 0)) continue;       // not this slab
            int la  = (int)(p1 & 0xFFFF) - base_w;
            int sft = (int)((p1 >> 16) & 31);
            int dyw = (int)((p1 >> 27) & 4);           // 0 or 4 words
            bool edge = s ? (zb == 128) : (zb == 0);
            int dz = edge ? 0 : 512;                   // hi-plane word offset
            u32 amv = (AM >> (4 * j)) & 15u;
            u32 glo = amv, ghi = amv;
            if (s) ghi = edge ? 0u : amv;              // zb==128: hi masked
            else   glo = edge ? 0u : amv;              // zb==0:  lo masked
            int l0 = la, l1 = la + dyw, l2 = la + dz, l3 = la + dz + dyw;
            u32 w00 = lds[l0], w01 = lds[l0 + 1];
            u32 w10 = lds[l1], w11 = lds[l1 + 1];
            u32 w20 = lds[l2], w21 = lds[l2 + 1];
            u32 w30 = lds[l3], w31 = lds[l3 + 1];
            u32 t0 = __builtin_amdgcn_alignbit(w01, w00, (u32)sft) & (glo & 3u);
            u32 t1 = __builtin_amdgcn_alignbit(w11, w10, (u32)sft) & ((glo >> 2) & 3u);
            u32 t2 = __builtin_amdgcn_alignbit(w21, w20, (u32)sft) & (ghi & 3u);
            u32 t3 = __builtin_amdgcn_alignbit(w31, w30, (u32)sft) & ((ghi >> 2) & 3u);
            float w = wx[j];
            int b0 = (int)(t0 & 1u), b1 = (int)(t1 & 1u);
            int b2 = (int)(t2 & 1u), b3 = (int)(t3 & 1u);
            float r00 = fmaf(w, (float)((int)(t0 >> 1) - b0), (float)b0);
            float r01 = fmaf(w, (float)((int)(t1 >> 1) - b1), (float)b1);
            float r10 = fmaf(w, (float)((int)(t2 >> 1) - b2), (float)b2);
            float r11 = fmaf(w, (float)((int)(t3 >> 1) - b3), (float)b3);
            float cy0 = fmaf(wy[j], r01 - r00, r00);
            float cy1 = fmaf(wy[j], r11 - r10, r10);
            o[j] = fmaf(wz[j], cy1 - cy0, cy0);
        }
    }
    fx4* o4 = (fx4*)out;
    fx4 r0 = {o[0], o[1], o[2], o[3]};
    fx4 r1 = {o[4], o[5], o[6], o[7]};
    o4[2 * T]     = r0;
    o4[2 * T + 1] = r1;
}

// ------------------------------------------------- fallback path ---------
__device__ __forceinline__ unsigned bit_at(u64 lo, u64 hi, int xi) {
    if ((unsigned)xi >= 128u) return 0u;
    u64 w = (xi < 64) ? lo : hi;
    return (unsigned)((w >> (xi & 63)) & 1ull);
}

__global__ __launch_bounds__(256)
void table_kernel(const u64* __restrict__ mask, unsigned char* __restrict__ tbl) {
    int i = blockIdx.x * blockDim.x + threadIdx.x;
    if (i >= (int)TBL_BYTES) return;
    int x = i % TD;
    int t = i / TD;
    int y = t % TD;
    int z = t / TD;
    int x0 = x - 1;
    unsigned byte = 0u;
#pragma unroll
    for (int dz = 0; dz < 2; ++dz) {
#pragma unroll
        for (int dy = 0; dy < 2; ++dy) {
            int yi = y - 1 + dy, zi = z - 1 + dz;
            u64 lo = 0ull, hi = 0ull;
            if (((unsigned)yi < 128u) & ((unsigned)zi < 128u)) {
                int r = (zi * 128 + yi) * 2;
                lo = mask[r];
                hi = mask[r + 1];
            }
            int kk = dy * 2 + dz * 4;
            byte |= (bit_at(lo, hi, x0) << kk) | (bit_at(lo, hi, x0 + 1) << (kk + 1));
        }
    }
    tbl[i] = (unsigned char)byte;
}

__global__ __launch_bounds__(256)
void sample_packed(const unsigned char* __restrict__ tbl,
                   const float* __restrict__ coords,
                   float* __restrict__ out, int nt) {
    int t = blockIdx.x * blockDim.x + threadIdx.x;
    if (t >= nt) return;
    const fx4* c4 = (const fx4*)coords;
    fx4 q[6];
#pragma unroll
    for (int j = 0; j < 6; ++j) q[j] = c4[6 * t + j];
    const float* f = (const float*)q;
    float wxa[8], wya[8], wza[8];
    int addr[8];
#pragma unroll
    for (int i = 0; i < 8; ++i) {
        float ix = fmaf(f[3 * i + 0], 64.0f, 63.5f);
        float iy = fmaf(f[3 * i + 1], 64.0f, 63.5f);
        float iz = fmaf(f[3 * i + 2], 64.0f, 63.5f);
        float fx = floorf(ix), fy = floorf(iy), fz = floorf(iz);
        wxa[i] = ix - fx; wya[i] = iy - fy; wza[i] = iz - fz;
        int xb = (int)fx + 1, yb = (int)fy + 1, zb = (int)fz + 1;
        addr[i] = (zb * TD + yb) * TD + xb;
    }
    unsigned bytes[8];
#pragma unroll
    for (int i = 0; i < 8; ++i) bytes[i] = (unsigned)tbl[addr[i]];
    float o[8];
#pragma unroll
    for (int i = 0; i < 8; ++i) {
        unsigned byte = bytes[i];
        float wx = wxa[i], wy = wya[i], wz = wza[i];
        float v0 = (float)( byte       & 1u);
        float v1 = (float)((byte >> 1) & 1u);
        float v2 = (float)((byte >> 2) & 1u);
        float v3 = (float)((byte >> 3) & 1u);
        float v4 = (float)((byte >> 4) & 1u);
        float v5 = (float)((byte >> 5) & 1u);
        float v6 = (float)((byte >> 6) & 1u);
        float v7 = (float)((byte >> 7) & 1u);
        float c00 = v0 + wx * (v1 - v0);
        float c10 = v2 + wx * (v3 - v2);
        float c01 = v4 + wx * (v5 - v4);
        float c11 = v6 + wx * (v7 - v6);
        float c0  = c00 + wy * (c10 - c00);
        float c1  = c01 + wy * (c11 - c01);
        o[i] = c0 + wz * (c1 - c0);
    }
    fx4* o4 = (fx4*)out;
    fx4 r0 = {o[0], o[1], o[2], o[3]};
    fx4 r1 = {o[4], o[5], o[6], o[7]};
    o4[2 * t + 0] = r0;
    o4[2 * t + 1] = r1;
}

// -------------------------------------------------------------- launch ----
extern "C" void kernel_launch(void* const* d_in, const int* in_sizes, int n_in,
                              void* d_out, int out_size, void* d_ws, size_t ws_size,
                              hipStream_t stream) {
    const float* grid   = (const float*)d_in[0];
    const float* coords = (const float*)d_in[1];
    float* out = (float*)d_out;
    int npts = in_sizes[1] / 3;                          // 8,388,608
    int vox = GS * GS * GS;

    u64* mask = (u64*)d_ws;                              // 256 KB @ offset 0

    // Probe legality of 133,124B dynamic LDS (capture-safe, deterministic).
    (void)hipFuncSetAttribute((const void*)sample_2p,
                              hipFuncAttributeMaxDynamicSharedMemorySize,
                              (int)SLAB_LDS);
    int nb = 0;
    hipError_t oe = hipOccupancyMaxActiveBlocksPerMultiprocessor(
        &nb, sample_2p, 1024, SLAB_LDS);
    bool slab_ok = (oe == hipSuccess) && (nb >= 1) && (ws_size >= MASK_BYTES) &&
                   (npts == 1024 * 8192);

    if (slab_ok) {
        bitpack_kernel<<<vox / 256, 256, 0, stream>>>(grid, mask);
        sample_2p<<<1024, 1024, SLAB_LDS, stream>>>((const u32*)mask, coords, out);
    } else if (ws_size >= WS_FB) {
        unsigned char* tbl = (unsigned char*)d_ws + TBL_OFF;
        bitpack_kernel<<<vox / 256, 256, 0, stream>>>(grid, mask);
        table_kernel<<<(int)((TBL_BYTES + 255) / 256), 256, 0, stream>>>(mask, tbl);
        int nt = npts / 8;
        sample_packed<<<(nt + 255) / 256, 256, 0, stream>>>(tbl, coords, out, nt);
    }
}